// Round 10
// baseline (11345.618 us; speedup 1.0000x reference)
//
#include <hip/hip_runtime.h>

// Problem constants (B,T,S,L,D_IN,OUT,W = 256,512,256,36,8,10,256)
#define Tt   512
#define Ll   36
#define DIN  8
#define OUTd 10

typedef __attribute__((ext_vector_type(8))) _Float16 half8;
typedef __attribute__((ext_vector_type(4))) float f32x4;

__device__ __forceinline__ unsigned short f2h(float f) {
    union { _Float16 h; unsigned short s; } u; u.h = (_Float16)f; return u.s;
}
__device__ __forceinline__ float h2f(unsigned short s) {
    union { unsigned short s; _Float16 h; } u; u.s = s; return (float)u.h;
}
__device__ __forceinline__ float sp_f(float x) {      // jax.nn.softplus
    return fmaxf(x, 0.f) + __logf(1.f + __expf(-fabsf(x)));
}
__device__ __forceinline__ float tanh_f(float x) {
    float e = __expf(2.f * x);
    return 1.f - 2.f / (e + 1.f);
}

// ---- agent-scope (sc1 / LLC-coherent) helpers: cross-XCD-safe ----
__device__ __forceinline__ unsigned long long ldg64(const void* p) {
    return __hip_atomic_load((const unsigned long long*)p, __ATOMIC_RELAXED, __HIP_MEMORY_SCOPE_AGENT);
}
__device__ __forceinline__ void stg64(void* p, unsigned long long v) {
    __hip_atomic_store((unsigned long long*)p, v, __ATOMIC_RELAXED, __HIP_MEMORY_SCOPE_AGENT);
}
__device__ __forceinline__ void sth(unsigned short* p, unsigned short v) {
    __hip_atomic_store(p, v, __ATOMIC_RELAXED, __HIP_MEMORY_SCOPE_AGENT);
}
union U64F2 { unsigned long long u; float f[2]; unsigned short s[4]; };
union S8U   { unsigned long long u[2]; half8 v; };

// ---- LDS layout (no h buffer: stage1 streams A directly from LLC — R10) ----
struct GScr {
    short z1[16*264];                  // stage-1 activations, fp16
    short z2[16*264];                  // stage-2 activations, fp16
    float lss[2*576];                  // logsigs slice, double-buffered
    float ml[16*584];                  // tanh(m) slice [16 rows x 576 n], f32
};                                      // ~59 KB
struct IScr { float x0s[32][DIN]; float h1[32*257]; float h2[32*257]; };
union  Scr  { GScr g; IScr in; };

// ---- full-grid tree barrier (phase 0 only); touches slots[0 .. 512] inclusive ----
__device__ __forceinline__ void gbar(int* bar, int gen) {
    __syncthreads();
    if (threadIdx.x == 0) {
        const int g = blockIdx.x & 7;
        int old = __hip_atomic_fetch_add(bar + g * 32, 1, __ATOMIC_RELAXED, __HIP_MEMORY_SCOPE_AGENT);
        if (old == gen * 32 - 1) {
            int o2 = __hip_atomic_fetch_add(bar + 8 * 32, 1, __ATOMIC_RELAXED, __HIP_MEMORY_SCOPE_AGENT);
            if (o2 == gen * 8 - 1) {
#pragma unroll
                for (int gg = 0; gg < 8; ++gg)
                    __hip_atomic_store(bar + (9 + gg) * 32, gen, __ATOMIC_RELAXED, __HIP_MEMORY_SCOPE_AGENT);
            }
        }
        while (__hip_atomic_load(bar + (9 + g) * 32, __ATOMIC_RELAXED, __HIP_MEMORY_SCOPE_AGENT) < gen)
            __builtin_amdgcn_s_sleep(2);
    }
    __syncthreads();
}

// cast 8 consecutive k of W[n][k] (N x 256) into frag-contiguous transposed fp16:
// element (n,k) -> ((k>>5)*N + n)*32 + ((k>>3)&3)*8 + (k&7)
__device__ __forceinline__ void cast_w8n_h(const float* src, unsigned short* dh,
                                           long u, int N) {
    long n = u >> 5; int k8 = (int)(u & 31);
    const float* sp = src + n * 256 + k8 * 8;
    f32x4 f0 = *(const f32x4*)sp;
    f32x4 f1 = *(const f32x4*)(sp + 4);
    U64F2 H0, H1;
#pragma unroll
    for (int q = 0; q < 4; ++q) {
        H0.s[q] = f2h(f0[q]);
        H1.s[q] = f2h(f1[q]);
    }
    long d = ((long)(k8 >> 2) * N + n) * 32 + (k8 & 3) * 8;
    stg64(dh + d, H0.u);  stg64(dh + d + 4, H1.u);
}

// stage with LDS A (stage 2): wave owns 4 n-tiles; WF[j][kt] register-resident B.
#define MLP_STAGE16R(Ah, WF, BIAS, Zh) do {                                                 \
    f32x4 acc_[4] = {zero4, zero4, zero4, zero4};                                            \
    _Pragma("unroll")                                                                        \
    for (int kt_ = 0; kt_ < 8; ++kt_) {                                                      \
      half8 ah_ = *(const half8*)(const void*)&(Ah)[l15 * 264 + kt_ * 32 + quad * 8];        \
      _Pragma("unroll")                                                                      \
      for (int j_ = 0; j_ < 4; ++j_)                                                         \
        acc_[j_] = __builtin_amdgcn_mfma_f32_16x16x32_f16(ah_, (WF)[j_][kt_], acc_[j_], 0, 0, 0); \
    }                                                                                        \
    _Pragma("unroll")                                                                        \
    for (int j_ = 0; j_ < 4; ++j_) {                                                         \
      int n_ = (4 * wv + j_) * 16 + l15;                                                     \
      float bs_ = (BIAS)[n_];                                                                \
      _Pragma("unroll")                                                                      \
      for (int r_ = 0; r_ < 4; ++r_) {                                                       \
        int row_ = quad * 4 + r_;                                                            \
        (Zh)[row_ * 264 + n_] = (short)f2h(sp_f(acc_[j_][r_] + bs_));                        \
      }                                                                                      \
    }                                                                                        \
  } while (0)

// stage 1: A streamed DIRECTLY from LLC h-buffer (no LDS gather, no sync needed).
// 16 independent ldg64/lane -> compiler pipelines them under the MFMAs.
#define MLP_STAGE16G(HS, WF, BIAS, Zh) do {                                                 \
    f32x4 acc_[4] = {zero4, zero4, zero4, zero4};                                            \
    _Pragma("unroll")                                                                        \
    for (int kt_ = 0; kt_ < 8; ++kt_) {                                                      \
      S8U a_;                                                                                \
      long go_ = (long)(b0c16 + l15) * 256 + kt_ * 32 + quad * 8;                            \
      a_.u[0] = ldg64((HS) + go_);                                                           \
      a_.u[1] = ldg64((HS) + go_ + 4);                                                       \
      _Pragma("unroll")                                                                      \
      for (int j_ = 0; j_ < 4; ++j_)                                                         \
        acc_[j_] = __builtin_amdgcn_mfma_f32_16x16x32_f16(a_.v, (WF)[j_][kt_], acc_[j_], 0, 0, 0); \
    }                                                                                        \
    _Pragma("unroll")                                                                        \
    for (int j_ = 0; j_ < 4; ++j_) {                                                         \
      int n_ = (4 * wv + j_) * 16 + l15;                                                     \
      float bs_ = (BIAS)[n_];                                                                \
      _Pragma("unroll")                                                                      \
      for (int r_ = 0; r_ < 4; ++r_) {                                                       \
        int row_ = quad * 4 + r_;                                                            \
        (Zh)[row_ * 264 + n_] = (short)f2h(sp_f(acc_[j_][r_] + bs_));                        \
      }                                                                                      \
    }                                                                                        \
  } while (0)

__global__ __launch_bounds__(256, 1) void rde_fused10(
    const float* __restrict__ x0, const float* __restrict__ logsigs,
    const float* __restrict__ iW1, const float* __restrict__ ib1,
    const float* __restrict__ iW2, const float* __restrict__ ib2,
    const float* __restrict__ iW3, const float* __restrict__ ib3,
    const float* __restrict__ vW1, const float* __restrict__ vb1,
    const float* __restrict__ vW2, const float* __restrict__ vb2,
    const float* __restrict__ vW3, const float* __restrict__ vb3,
    const float* __restrict__ roW, const float* __restrict__ rob,
    float* __restrict__ out,
    unsigned short* hA, unsigned short* hB, unsigned short* hC,
    unsigned short* w1t, unsigned short* w2t, unsigned short* w3t, int* slots) {
    __shared__ Scr S;
    __shared__ float hloc[256];   // owned h sub-tile [16 rows x 16 s], exact f32
    const int tid = threadIdx.x, blk = blockIdx.x;
    const int lane = tid & 63, wv = tid >> 6, quad = lane >> 4, l15 = lane & 15;
    // chunk = (blk>>3)&15, slot = ((blk&7)<<1)|(blk>>7): each XCD's 32 blocks share
    // only 2 W3 slices -> L2-resident (R6 lesson: 1 block/CU + synced chunks mandatory).
    const int chunk = (blk >> 3) & 15;
    const int sl = ((blk & 7) << 1) | (blk >> 7);
    const int b0c16 = chunk * 16;        // 16 batch rows owned by this chunk
    const int s0g = sl * 16;             // owned s-slice
    const int n0g = sl * 576;            // owned W3 n-slice
    // R10: per-slot publish flags (monotone step counts). flags[sl] == n means this
    // slot's columns of h(n) are visible at LLC. One writer per flag -> release STORE,
    // no RMW. Region [1024,1280) of slots: disjoint from gbar's [0,512].
    int* flags = slots + 1024 + chunk * 16;
    const f32x4 zero4 = {0.f, 0.f, 0.f, 0.f};

    // ===== phase 0: init MLP (blk<8), W1/W2 fp16 cast (8..15), W3 fp16 cast (16..255) =====
    if (blk < 8) {
        IScr& I = S.in;
        const int b0 = blk * 32;
        I.x0s[tid >> 3][tid & 7] = x0[(b0 + (tid >> 3)) * DIN + (tid & 7)];
        __syncthreads();
        const int j = tid;
        {
            float w[DIN];
#pragma unroll
            for (int k = 0; k < DIN; ++k) w[k] = iW1[j * DIN + k];
            float bias = ib1[j];
            for (int r = 0; r < 32; ++r) {
                float acc = bias;
#pragma unroll
                for (int k = 0; k < DIN; ++k) acc += I.x0s[r][k] * w[k];
                I.h1[r * 257 + j] = sp_f(acc);
            }
        }
        __syncthreads();
        {
            float bias = ib2[j];
            for (int rb = 0; rb < 4; ++rb) {
                float a8[8];
#pragma unroll
                for (int rr = 0; rr < 8; ++rr) a8[rr] = bias;
                for (int k = 0; k < 256; ++k) {
                    float wvv = iW2[j * 256 + k];
#pragma unroll
                    for (int rr = 0; rr < 8; ++rr) a8[rr] += I.h1[(rb * 8 + rr) * 257 + k] * wvv;
                }
#pragma unroll
                for (int rr = 0; rr < 8; ++rr) I.h2[(rb * 8 + rr) * 257 + j] = sp_f(a8[rr]);
            }
        }
        __syncthreads();
        {
            float bias = ib3[j];
            for (int rb = 0; rb < 4; ++rb) {
                float a8[8];
#pragma unroll
                for (int rr = 0; rr < 8; ++rr) a8[rr] = bias;
                for (int k = 0; k < 256; ++k) {
                    float wvv = iW3[j * 256 + k];
#pragma unroll
                    for (int rr = 0; rr < 8; ++rr) a8[rr] += I.h2[(rb * 8 + rr) * 257 + k] * wvv;
                }
#pragma unroll
                for (int rr = 0; rr < 8; ++rr)   // publish h0 as fp16 into buffer 0
                    sth(&hA[(b0 + rb * 8 + rr) * 256 + j], f2h(a8[rr]));
            }
        }
    } else if (blk < 16) {
        const int idx = blk - 8;
        const float* src = (idx < 4) ? vW1 : vW2;
        unsigned short* dh = (idx < 4) ? w1t : w2t;
        const int part = idx & 3;
        for (int u = part * 2048 + tid; u < (part + 1) * 2048; u += 256)
            cast_w8n_h(src, dh, u, 256);
    } else {
        for (long u = (long)(blk - 16) * 256 + tid; u < 9216L * 32; u += 240L * 256)
            cast_w8n_h(vW3, w3t, u, 9216);
    }
    gbar(slots, 1);

    // ===== load this wave's W1/W2 B-fragments into registers (t-invariant, R9) =====
    half8 w1f[4][8], w2f[4][8];
#pragma unroll
    for (int j = 0; j < 4; ++j) {
        int n_ = (4 * wv + j) * 16 + l15;
#pragma unroll
        for (int kt = 0; kt < 8; ++kt) {
            long bo = ((long)kt * 256 + n_) * 32 + quad * 8;
            w1f[j][kt] = *(const half8*)(const void*)(w1t + bo);
            w2f[j][kt] = *(const half8*)(const void*)(w2t + bo);
        }
    }

    // init owned h sub-tile (fp16 -> f32; owned trajectory accumulates in exact f32)
    if (tid < 64) {
        int r = tid >> 2, sq = tid & 3;
        U64F2 a;
        a.u = ldg64(hA + (b0c16 + r) * 256 + s0g + sq * 4);
#pragma unroll
        for (int q = 0; q < 4; ++q) hloc[r * 16 + sq * 4 + q] = h2f(a.s[q]);
    }
    // prefetch logsigs slice for t=0 into buffer 0
    for (int i = tid; i < 16 * Ll; i += 256) {
        int r = i / Ll, l = i - r * Ll;
        S.g.lss[i] = logsigs[((long)(b0c16 + r) * Tt) * Ll + l];
    }
    __syncthreads();

    // 3-buffer rotation. Safety: a block at step t saw all flags >= t, i.e. every
    // block finished step t-1. Writer at t targets buf[(t+1)%3]; the only readers of
    // that physical buffer are step t-2 (h(t-2)) readers, all done. Drift <= 1 step.
    const unsigned short* h_r = hA;   // read  h(t)
    unsigned short*       h_w = hB;   // write h(t+1)
    unsigned short*       h_s = hC;   // spare (h(t-1), being retired)

    // ================= main scan: flag-gated, no counter barrier =================
    for (int t = 0; t < Tt; ++t) {
        GScr& G = S.g;

        // ---- wait: all 16 slot flags >= t (lanes 0..15 poll in parallel) ----
        for (;;) {
            int v = t;
            if (lane < 16)
                v = __hip_atomic_load(flags + lane, __ATOMIC_RELAXED, __HIP_MEMORY_SCOPE_AGENT);
            if (__all(v >= t)) break;
            __builtin_amdgcn_s_sleep(1);
        }

        // ---- readout of out[b0c16+sl, t, :] (wave 0 only; shfl-reduce, no LDS) ----
        if (wv == 0) {
            U64F2 a;
            a.u = ldg64(h_r + (long)(b0c16 + sl) * 256 + lane * 4);
            float hv[4];
#pragma unroll
            for (int q = 0; q < 4; ++q) hv[q] = h2f(a.s[q]);
            float pacc[OUTd];
#pragma unroll
            for (int o = 0; o < OUTd; ++o) {
                f32x4 w4 = *(const f32x4*)(roW + o * 256 + lane * 4);
                pacc[o] = hv[0] * w4[0] + hv[1] * w4[1] + hv[2] * w4[2] + hv[3] * w4[3];
            }
#pragma unroll
            for (int o = 0; o < OUTd; ++o) {
                float v = pacc[o];
#pragma unroll
                for (int off = 32; off; off >>= 1) v += __shfl_down(v, off);
                if (lane == 0)
                    out[((long)(b0c16 + sl) * 513 + t) * OUTd + o] = rob[o] + v;
            }
        }

        // ---- stage 1: z1 = sp(h W1^T), A streamed from LLC ----
        MLP_STAGE16G(h_r, w1f, vb1, G.z1);
        __syncthreads();

        // ---- stage 2: z2 = sp(z1 W2^T), B register-resident ----
        MLP_STAGE16R(G.z1, w2f, vb2, G.z2);
        __syncthreads();

        // ---- W3 GEMM: m-pre = z2 @ W3slice^T (fp16, streamed from L2) ----
        {
            f32x4 acc[9];
#pragma unroll
            for (int nt = 0; nt < 9; ++nt) acc[nt] = zero4;
            for (int kk = 0; kk < 8; ++kk) {
                half8 ah = *(const half8*)(const void*)&G.z2[l15 * 264 + kk * 32 + quad * 8];
#pragma unroll
                for (int nt = 0; nt < 9; ++nt) {
                    long n = (long)n0g + wv * 144 + nt * 16 + l15;
                    long bo = ((long)kk * 9216 + n) * 32 + quad * 8;
                    half8 bh = *(const half8*)(const void*)(w3t + bo);
                    acc[nt] = __builtin_amdgcn_mfma_f32_16x16x32_f16(ah, bh, acc[nt], 0, 0, 0);
                }
            }
            // tanh epilogue -> ml
#pragma unroll
            for (int nt = 0; nt < 9; ++nt) {
                int nloc = wv * 144 + nt * 16 + l15;
                float bias = vb3[n0g + nloc];
#pragma unroll
                for (int r = 0; r < 4; ++r) {
                    int row = quad * 4 + r;
                    G.ml[row * 584 + nloc] = tanh_f(acc[nt][r] + bias);
                }
            }
        }
        __syncthreads();

        // ---- l-contraction: thread (r, sL) owns h[r][s0g+sL]: hloc += dot36 ----
        {
            int r = tid >> 4, sL = tid & 15;
            const f32x4* mp = (const f32x4*)(const void*)&G.ml[r * 584 + sL * 36];
            const f32x4* lp = (const f32x4*)(const void*)&G.lss[(t & 1) * 576 + r * 36];
            float a = 0.f;
#pragma unroll
            for (int q = 0; q < 9; ++q) {
                f32x4 m4 = mp[q], l4 = lp[q];
                a += m4[0] * l4[0] + m4[1] * l4[1] + m4[2] * l4[2] + m4[3] * l4[3];
            }
            hloc[tid] += a;
        }
        __syncthreads();   // hloc complete (publish below reads all of it)

        // ---- publish owned h sub-tile fp16 (wave 0), then RELEASE-store own flag ----
        if (tid < 64) {
            int r = tid >> 2, sq = tid & 3;
            U64F2 H;
#pragma unroll
            for (int q = 0; q < 4; ++q) H.s[q] = f2h(hloc[r * 16 + sq * 4 + q]);
            stg64(h_w + (b0c16 + r) * 256 + s0g + sq * 4, H.u);
        }
        if (tid == 0)   // release: drains wave 0's publish stores (same wave) first
            __hip_atomic_store(flags + sl, t + 1, __ATOMIC_RELEASE, __HIP_MEMORY_SCOPE_AGENT);

        // ---- overlap: prefetch logsigs(t+1) (h-independent) ----
        if (t + 1 < Tt) {
            for (int i = tid; i < 16 * Ll; i += 256) {
                int r = i / Ll, l = i - r * Ll;
                G.lss[((t + 1) & 1) * 576 + i] =
                    logsigs[((long)(b0c16 + r) * Tt + (t + 1)) * Ll + l];
            }
        }

        // rotate buffers: next read = current write; next write = spare
        {
            const unsigned short* t0 = h_r;
            h_r = h_w; h_w = h_s; h_s = (unsigned short*)t0;
        }
    }

    // ---- final readout out[:, 512, :] from h(512) = h_r after 512 rotations ----
    {
        for (;;) {
            int v = Tt;
            if (lane < 16)
                v = __hip_atomic_load(flags + lane, __ATOMIC_RELAXED, __HIP_MEMORY_SCOPE_AGENT);
            if (__all(v >= Tt)) break;
            __builtin_amdgcn_s_sleep(1);
        }
        if (wv == 0) {
            U64F2 a;
            a.u = ldg64(h_r + (long)(b0c16 + sl) * 256 + lane * 4);
            float hv[4];
#pragma unroll
            for (int q = 0; q < 4; ++q) hv[q] = h2f(a.s[q]);
            float pacc[OUTd];
#pragma unroll
            for (int o = 0; o < OUTd; ++o) {
                f32x4 w4 = *(const f32x4*)(roW + o * 256 + lane * 4);
                pacc[o] = hv[0] * w4[0] + hv[1] * w4[1] + hv[2] * w4[2] + hv[3] * w4[3];
            }
#pragma unroll
            for (int o = 0; o < OUTd; ++o) {
                float v = pacc[o];
#pragma unroll
                for (int off = 32; off; off >>= 1) v += __shfl_down(v, off);
                if (lane == 0)
                    out[((long)(b0c16 + sl) * 513 + Tt) * OUTd + o] = rob[o] + v;
            }
        }
    }
}

extern "C" void kernel_launch(void* const* d_in, const int* in_sizes, int n_in,
                              void* d_out, int out_size, void* d_ws, size_t ws_size,
                              hipStream_t stream) {
    const float* x0      = (const float*)d_in[0];
    const float* logsigs = (const float*)d_in[1];
    const float* iW1 = (const float*)d_in[2];
    const float* ib1 = (const float*)d_in[3];
    const float* iW2 = (const float*)d_in[4];
    const float* ib2 = (const float*)d_in[5];
    const float* iW3 = (const float*)d_in[6];
    const float* ib3 = (const float*)d_in[7];
    const float* vW1 = (const float*)d_in[8];
    const float* vb1 = (const float*)d_in[9];
    const float* vW2 = (const float*)d_in[10];
    const float* vb2 = (const float*)d_in[11];
    const float* vW3 = (const float*)d_in[12];
    const float* vb3 = (const float*)d_in[13];
    const float* roW = (const float*)d_in[14];
    const float* rob = (const float*)d_in[15];
    float* out = (float*)d_out;

    char* p = (char*)d_ws;
    unsigned short* hA   = (unsigned short*)p;                // 131072 B (fp16, buf 0)
    unsigned short* hB   = (unsigned short*)(p + 131072);     // 131072 B (buf 1)
    unsigned short* hC   = (unsigned short*)(p + 262144);     // 131072 B (buf 2)
    unsigned short* w1t  = (unsigned short*)(p + 393216);     // 131072 B (fp16)
    unsigned short* w2t  = (unsigned short*)(p + 524288);     // 131072 B (fp16)
    unsigned short* w3t  = (unsigned short*)(p + 655360);     // 4718592 B (fp16)
    int* slots           = (int*)(p + 10485760);              // gbar [0,512], flags [1024,1280)

    hipMemsetAsync(slots, 0, 8192, stream);
    rde_fused10<<<dim3(256), dim3(256), 0, stream>>>(
        x0, logsigs, iW1, ib1, iW2, ib2, iW3, ib3,
        vW1, vb1, vW2, vb2, vW3, vb3, roW, rob, out,
        hA, hB, hC, w1t, w2t, w3t, slots);
}

// Round 11
// 10109.058 us; speedup vs baseline: 1.1223x; 1.1223x over previous
//
#include <hip/hip_runtime.h>

// Problem constants (B,T,S,L,D_IN,OUT,W = 256,512,256,36,8,10,256)
#define Tt   512
#define Ll   36
#define DIN  8
#define OUTd 10

typedef __attribute__((ext_vector_type(8))) _Float16 half8;
typedef __attribute__((ext_vector_type(4))) float f32x4;

__device__ __forceinline__ unsigned short f2h(float f) {
    union { _Float16 h; unsigned short s; } u; u.h = (_Float16)f; return u.s;
}
__device__ __forceinline__ float h2f(unsigned short s) {
    union { unsigned short s; _Float16 h; } u; u.s = s; return (float)u.h;
}
__device__ __forceinline__ float sp_f(float x) {      // jax.nn.softplus
    return fmaxf(x, 0.f) + __logf(1.f + __expf(-fabsf(x)));
}
__device__ __forceinline__ float tanh_f(float x) {
    float e = __expf(2.f * x);
    return 1.f - 2.f / (e + 1.f);
}

// ---- agent-scope (sc1 / LLC-coherent) helpers: cross-XCD-safe ----
__device__ __forceinline__ unsigned long long ldg64(const void* p) {
    return __hip_atomic_load((const unsigned long long*)p, __ATOMIC_RELAXED, __HIP_MEMORY_SCOPE_AGENT);
}
__device__ __forceinline__ void stg64(void* p, unsigned long long v) {
    __hip_atomic_store((unsigned long long*)p, v, __ATOMIC_RELAXED, __HIP_MEMORY_SCOPE_AGENT);
}
__device__ __forceinline__ void sth(unsigned short* p, unsigned short v) {
    __hip_atomic_store(p, v, __ATOMIC_RELAXED, __HIP_MEMORY_SCOPE_AGENT);
}
union U64F2 { unsigned long long u; float f[2]; unsigned short s[4]; };

// ---- LDS layout (all activations single-plane fp16) ----
struct GScr {
    short hh[16*264];                  // gathered h(t), fp16
    short z1[16*264];                  // stage-1 activations, fp16
    short z2[16*264];                  // stage-2 activations, fp16
    float lss[2*576];                  // logsigs slice, double-buffered
    float ml[16*584];                  // tanh(m) slice [16 rows x 576 n], f32
};                                      // ~67 KB
struct IScr { float x0s[32][DIN]; float h1[32*257]; float h2[32*257]; };
union  Scr  { GScr g; IScr in; };

// ---- full-grid tree barrier (phase 0 only); touches slots[0 .. 512] inclusive ----
__device__ __forceinline__ void gbar(int* bar, int gen) {
    __syncthreads();
    if (threadIdx.x == 0) {
        const int g = blockIdx.x & 7;
        int old = __hip_atomic_fetch_add(bar + g * 32, 1, __ATOMIC_RELAXED, __HIP_MEMORY_SCOPE_AGENT);
        if (old == gen * 32 - 1) {
            int o2 = __hip_atomic_fetch_add(bar + 8 * 32, 1, __ATOMIC_RELAXED, __HIP_MEMORY_SCOPE_AGENT);
            if (o2 == gen * 8 - 1) {
#pragma unroll
                for (int gg = 0; gg < 8; ++gg)
                    __hip_atomic_store(bar + (9 + gg) * 32, gen, __ATOMIC_RELAXED, __HIP_MEMORY_SCOPE_AGENT);
            }
        }
        while (__hip_atomic_load(bar + (9 + g) * 32, __ATOMIC_RELAXED, __HIP_MEMORY_SCOPE_AGENT) < gen)
            __builtin_amdgcn_s_sleep(2);
    }
    __syncthreads();
}

// cast 8 consecutive k of W[n][k] (N x 256) into frag-contiguous transposed fp16:
// element (n,k) -> ((k>>5)*N + n)*32 + ((k>>3)&3)*8 + (k&7)
__device__ __forceinline__ void cast_w8n_h(const float* src, unsigned short* dh,
                                           long u, int N) {
    long n = u >> 5; int k8 = (int)(u & 31);
    const float* sp = src + n * 256 + k8 * 8;
    f32x4 f0 = *(const f32x4*)sp;
    f32x4 f1 = *(const f32x4*)(sp + 4);
    U64F2 H0, H1;
#pragma unroll
    for (int q = 0; q < 4; ++q) {
        H0.s[q] = f2h(f0[q]);
        H1.s[q] = f2h(f1[q]);
    }
    long d = ((long)(k8 >> 2) * N + n) * 32 + (k8 & 3) * 8;
    stg64(dh + d, H0.u);  stg64(dh + d + 4, H1.u);
}

// one MLP stage for 16 rows, 4-wave, fp16, register-resident B (R9):
// wave owns 4 n-tiles; WF[j][kt] holds the B-fragment. All indices static.
#define MLP_STAGE16R(Ah, WF, BIAS, Zh) do {                                                 \
    f32x4 acc_[4] = {zero4, zero4, zero4, zero4};                                            \
    _Pragma("unroll")                                                                        \
    for (int kt_ = 0; kt_ < 8; ++kt_) {                                                      \
      half8 ah_ = *(const half8*)(const void*)&(Ah)[l15 * 264 + kt_ * 32 + quad * 8];        \
      _Pragma("unroll")                                                                      \
      for (int j_ = 0; j_ < 4; ++j_)                                                         \
        acc_[j_] = __builtin_amdgcn_mfma_f32_16x16x32_f16(ah_, (WF)[j_][kt_], acc_[j_], 0, 0, 0); \
    }                                                                                        \
    _Pragma("unroll")                                                                        \
    for (int j_ = 0; j_ < 4; ++j_) {                                                         \
      int n_ = (4 * wv + j_) * 16 + l15;                                                     \
      float bs_ = (BIAS)[n_];                                                                \
      _Pragma("unroll")                                                                      \
      for (int r_ = 0; r_ < 4; ++r_) {                                                       \
        int row_ = quad * 4 + r_;                                                            \
        (Zh)[row_ * 264 + n_] = (short)f2h(sp_f(acc_[j_][r_] + bs_));                        \
      }                                                                                      \
    }                                                                                        \
  } while (0)

__global__ __launch_bounds__(256, 1) void rde_fused11(
    const float* __restrict__ x0, const float* __restrict__ logsigs,
    const float* __restrict__ iW1, const float* __restrict__ ib1,
    const float* __restrict__ iW2, const float* __restrict__ ib2,
    const float* __restrict__ iW3, const float* __restrict__ ib3,
    const float* __restrict__ vW1, const float* __restrict__ vb1,
    const float* __restrict__ vW2, const float* __restrict__ vb2,
    const float* __restrict__ vW3, const float* __restrict__ vb3,
    const float* __restrict__ roW, const float* __restrict__ rob,
    float* __restrict__ out,
    unsigned short* hA, unsigned short* hB, unsigned short* hC,
    unsigned short* w1t, unsigned short* w2t, unsigned short* w3t, int* slots) {
    __shared__ Scr S;
    __shared__ float hloc[256];   // owned h sub-tile [16 rows x 16 s], exact f32
    __shared__ float rtmp[44];    // readout partials (4 waves x 10)
    const int tid = threadIdx.x, blk = blockIdx.x;
    const int lane = tid & 63, wv = tid >> 6, quad = lane >> 4, l15 = lane & 15;
    // chunk = (blk>>3)&15, slot = ((blk&7)<<1)|(blk>>7): each XCD's 32 blocks share
    // only 2 W3 slices -> L2-resident (R6 lesson: 1 block/CU + synced chunks mandatory).
    const int chunk = (blk >> 3) & 15;
    const int sl = ((blk & 7) << 1) | (blk >> 7);
    const int b0c16 = chunk * 16;        // 16 batch rows owned by this chunk
    const int s0g = sl * 16;             // owned s-slice
    const int n0g = sl * 576;            // owned W3 n-slice
    // R11: per-slot publish flags (monotone step counts); one writer each -> release
    // STORE, no RMW chain. Region [1024,1280) of slots, disjoint from gbar's [0,512].
    int* flags = slots + 1024 + chunk * 16;
    const f32x4 zero4 = {0.f, 0.f, 0.f, 0.f};

    // ===== phase 0: init MLP (blk<8), W1/W2 fp16 cast (8..15), W3 fp16 cast (16..255) =====
    if (blk < 8) {
        IScr& I = S.in;
        const int b0 = blk * 32;
        I.x0s[tid >> 3][tid & 7] = x0[(b0 + (tid >> 3)) * DIN + (tid & 7)];
        __syncthreads();
        const int j = tid;
        {
            float w[DIN];
#pragma unroll
            for (int k = 0; k < DIN; ++k) w[k] = iW1[j * DIN + k];
            float bias = ib1[j];
            for (int r = 0; r < 32; ++r) {
                float acc = bias;
#pragma unroll
                for (int k = 0; k < DIN; ++k) acc += I.x0s[r][k] * w[k];
                I.h1[r * 257 + j] = sp_f(acc);
            }
        }
        __syncthreads();
        {
            float bias = ib2[j];
            for (int rb = 0; rb < 4; ++rb) {
                float a8[8];
#pragma unroll
                for (int rr = 0; rr < 8; ++rr) a8[rr] = bias;
                for (int k = 0; k < 256; ++k) {
                    float wvv = iW2[j * 256 + k];
#pragma unroll
                    for (int rr = 0; rr < 8; ++rr) a8[rr] += I.h1[(rb * 8 + rr) * 257 + k] * wvv;
                }
#pragma unroll
                for (int rr = 0; rr < 8; ++rr) I.h2[(rb * 8 + rr) * 257 + j] = sp_f(a8[rr]);
            }
        }
        __syncthreads();
        {
            float bias = ib3[j];
            for (int rb = 0; rb < 4; ++rb) {
                float a8[8];
#pragma unroll
                for (int rr = 0; rr < 8; ++rr) a8[rr] = bias;
                for (int k = 0; k < 256; ++k) {
                    float wvv = iW3[j * 256 + k];
#pragma unroll
                    for (int rr = 0; rr < 8; ++rr) a8[rr] += I.h2[(rb * 8 + rr) * 257 + k] * wvv;
                }
#pragma unroll
                for (int rr = 0; rr < 8; ++rr)   // publish h0 as fp16 into buffer 0
                    sth(&hA[(b0 + rb * 8 + rr) * 256 + j], f2h(a8[rr]));
            }
        }
    } else if (blk < 16) {
        const int idx = blk - 8;
        const float* src = (idx < 4) ? vW1 : vW2;
        unsigned short* dh = (idx < 4) ? w1t : w2t;
        const int part = idx & 3;
        for (int u = part * 2048 + tid; u < (part + 1) * 2048; u += 256)
            cast_w8n_h(src, dh, u, 256);
    } else {
        for (long u = (long)(blk - 16) * 256 + tid; u < 9216L * 32; u += 240L * 256)
            cast_w8n_h(vW3, w3t, u, 9216);
    }
    gbar(slots, 1);

    // ===== load this wave's W1/W2 B-fragments into registers (t-invariant) =====
    half8 w1f[4][8], w2f[4][8];
#pragma unroll
    for (int j = 0; j < 4; ++j) {
        int n_ = (4 * wv + j) * 16 + l15;
#pragma unroll
        for (int kt = 0; kt < 8; ++kt) {
            long bo = ((long)kt * 256 + n_) * 32 + quad * 8;
            w1f[j][kt] = *(const half8*)(const void*)(w1t + bo);
            w2f[j][kt] = *(const half8*)(const void*)(w2t + bo);
        }
    }

    // init owned h sub-tile (fp16 -> f32; owned trajectory accumulates in exact f32)
    if (tid < 64) {
        int r = tid >> 2, sq = tid & 3;
        U64F2 a;
        a.u = ldg64(hA + (b0c16 + r) * 256 + s0g + sq * 4);
#pragma unroll
        for (int q = 0; q < 4; ++q) hloc[r * 16 + sq * 4 + q] = h2f(a.s[q]);
    }
    // prefetch logsigs slice for t=0 into buffer 0
    for (int i = tid; i < 16 * Ll; i += 256) {
        int r = i / Ll, l = i - r * Ll;
        S.g.lss[i] = logsigs[((long)(b0c16 + r) * Tt) * Ll + l];
    }
    __syncthreads();

    // 3-buffer rotation. flags>=t gating guarantees every block has finished its
    // publish of h(t) (end of its iteration t-1) before anyone reads h(t); the
    // writer of h(t+1) therefore can never collide with a live reader.
    const unsigned short* h_r = hA;   // read  h(t)
    unsigned short*       h_w = hB;   // write h(t+1)
    unsigned short*       h_s = hC;   // spare

    // ================= main scan: flag-gated, no counter barrier =================
    for (int t = 0; t < Tt; ++t) {
        GScr& G = S.g;

        // ---- wait: all 16 slot flags >= t (lanes 0..15 poll in parallel) ----
        for (;;) {
            int v = t;
            if (lane < 16)
                v = __hip_atomic_load(flags + lane, __ATOMIC_RELAXED, __HIP_MEMORY_SCOPE_AGENT);
            if (__all(v >= t)) break;
            __builtin_amdgcn_s_sleep(1);
        }

        // ---- gather h(t) [16 rows x 256] fp16 into LDS (coalesced u64 copies) ----
        for (int u = tid; u < 1024; u += 256) {
            int r = u >> 6, c4 = (u & 63) * 4;
            *(unsigned long long*)(void*)&G.hh[r * 264 + c4] = ldg64(h_r + (b0c16 + r) * 256 + c4);
        }
        __syncthreads();

        // ---- readout partials for row b0c16+sl (overlapped with stage 1) ----
        if (lane < OUTd) {
            const int o = lane;
            float acc = 0.f;
            const short* ph = &G.hh[sl * 264 + wv * 64];
            const float* wp = roW + o * 256 + wv * 64;
            for (int s = 0; s < 64; s += 8) {
                half8 vh = *(const half8*)(const void*)(ph + s);
                f32x4 w0 = *(const f32x4*)(wp + s);
                f32x4 w1 = *(const f32x4*)(wp + s + 4);
#pragma unroll
                for (int q = 0; q < 4; ++q) {
                    acc += (float)vh[q] * w0[q];
                    acc += (float)vh[q + 4] * w1[q];
                }
            }
            rtmp[wv * 10 + o] = acc;
        }

        // ---- stage 1: z1 = sp(h W1^T)  (B register-resident) ----
        MLP_STAGE16R(G.hh, w1f, vb1, G.z1);
        __syncthreads();

        if (tid < OUTd)
            out[((long)(b0c16 + sl) * 513 + t) * OUTd + tid] =
                rob[tid] + rtmp[tid] + rtmp[10 + tid] + rtmp[20 + tid] + rtmp[30 + tid];

        // ---- stage 2: z2 = sp(z1 W2^T)  (B register-resident) ----
        MLP_STAGE16R(G.z1, w2f, vb2, G.z2);
        __syncthreads();

        // ---- W3 GEMM: m-pre = z2 @ W3slice^T (fp16, streamed from L2) ----
        {
            f32x4 acc[9];
#pragma unroll
            for (int nt = 0; nt < 9; ++nt) acc[nt] = zero4;
            for (int kk = 0; kk < 8; ++kk) {
                half8 ah = *(const half8*)(const void*)&G.z2[l15 * 264 + kk * 32 + quad * 8];
#pragma unroll
                for (int nt = 0; nt < 9; ++nt) {
                    long n = (long)n0g + wv * 144 + nt * 16 + l15;
                    long bo = ((long)kk * 9216 + n) * 32 + quad * 8;
                    half8 bh = *(const half8*)(const void*)(w3t + bo);
                    acc[nt] = __builtin_amdgcn_mfma_f32_16x16x32_f16(ah, bh, acc[nt], 0, 0, 0);
                }
            }
            // tanh epilogue -> ml
#pragma unroll
            for (int nt = 0; nt < 9; ++nt) {
                int nloc = wv * 144 + nt * 16 + l15;
                float bias = vb3[n0g + nloc];
#pragma unroll
                for (int r = 0; r < 4; ++r) {
                    int row = quad * 4 + r;
                    G.ml[row * 584 + nloc] = tanh_f(acc[nt][r] + bias);
                }
            }
        }
        __syncthreads();

        // ---- l-contraction: thread (r, sL) owns h[r][s0g+sL]: hloc += dot36 ----
        {
            int r = tid >> 4, sL = tid & 15;
            const f32x4* mp = (const f32x4*)(const void*)&G.ml[r * 584 + sL * 36];
            const f32x4* lp = (const f32x4*)(const void*)&G.lss[(t & 1) * 576 + r * 36];
            float a = 0.f;
#pragma unroll
            for (int q = 0; q < 9; ++q) {
                f32x4 m4 = mp[q], l4 = lp[q];
                a += m4[0] * l4[0] + m4[1] * l4[1] + m4[2] * l4[2] + m4[3] * l4[3];
            }
            hloc[tid] += a;
        }
        __syncthreads();   // hloc complete (publish below reads all of it)

        // ---- publish owned h sub-tile fp16 (wave 0), then RELEASE-store own flag ----
        if (tid < 64) {
            int r = tid >> 2, sq = tid & 3;
            U64F2 H;
#pragma unroll
            for (int q = 0; q < 4; ++q) H.s[q] = f2h(hloc[r * 16 + sq * 4 + q]);
            stg64(h_w + (b0c16 + r) * 256 + s0g + sq * 4, H.u);
        }
        if (tid == 0)   // release orders wave 0's publish stores before the flag
            __hip_atomic_store(flags + sl, t + 1, __ATOMIC_RELEASE, __HIP_MEMORY_SCOPE_AGENT);

        // ---- overlap: prefetch logsigs(t+1) (h-independent) ----
        if (t + 1 < Tt) {
            for (int i = tid; i < 16 * Ll; i += 256) {
                int r = i / Ll, l = i - r * Ll;
                G.lss[((t + 1) & 1) * 576 + i] =
                    logsigs[((long)(b0c16 + r) * Tt + (t + 1)) * Ll + l];
            }
        }

        // rotate buffers: next read = current write; next write = spare
        {
            const unsigned short* t0 = h_r;
            h_r = h_w; h_w = h_s; h_s = (unsigned short*)t0;
        }
    }

    // ---- final readout out[:, 512, :] from h(512) = h_r after 512 rotations ----
    {
        for (;;) {
            int v = Tt;
            if (lane < 16)
                v = __hip_atomic_load(flags + lane, __ATOMIC_RELAXED, __HIP_MEMORY_SCOPE_AGENT);
            if (__all(v >= Tt)) break;
            __builtin_amdgcn_s_sleep(1);
        }
        __syncthreads();
        float* fb = S.g.ml;   // reuse as f32 row buffer
        if (tid < 64) {
            U64F2 a;
            a.u = ldg64(h_r + (long)(b0c16 + sl) * 256 + tid * 4);
#pragma unroll
            for (int q = 0; q < 4; ++q) fb[tid * 4 + q] = h2f(a.s[q]);
        }
        __syncthreads();
        if (tid < OUTd) {
            float acc = rob[tid];
            const float* wp = roW + tid * 256;
            for (int s = 0; s < 256; s += 4) {
                f32x4 hv = *(const f32x4*)(fb + s);
                f32x4 w4 = *(const f32x4*)(wp + s);
                acc += hv[0] * w4[0] + hv[1] * w4[1] + hv[2] * w4[2] + hv[3] * w4[3];
            }
            out[((long)(b0c16 + sl) * 513 + Tt) * OUTd + tid] = acc;
        }
    }
}

extern "C" void kernel_launch(void* const* d_in, const int* in_sizes, int n_in,
                              void* d_out, int out_size, void* d_ws, size_t ws_size,
                              hipStream_t stream) {
    const float* x0      = (const float*)d_in[0];
    const float* logsigs = (const float*)d_in[1];
    const float* iW1 = (const float*)d_in[2];
    const float* ib1 = (const float*)d_in[3];
    const float* iW2 = (const float*)d_in[4];
    const float* ib2 = (const float*)d_in[5];
    const float* iW3 = (const float*)d_in[6];
    const float* ib3 = (const float*)d_in[7];
    const float* vW1 = (const float*)d_in[8];
    const float* vb1 = (const float*)d_in[9];
    const float* vW2 = (const float*)d_in[10];
    const float* vb2 = (const float*)d_in[11];
    const float* vW3 = (const float*)d_in[12];
    const float* vb3 = (const float*)d_in[13];
    const float* roW = (const float*)d_in[14];
    const float* rob = (const float*)d_in[15];
    float* out = (float*)d_out;

    char* p = (char*)d_ws;
    unsigned short* hA   = (unsigned short*)p;                // 131072 B (fp16, buf 0)
    unsigned short* hB   = (unsigned short*)(p + 131072);     // 131072 B (buf 1)
    unsigned short* hC   = (unsigned short*)(p + 262144);     // 131072 B (buf 2)
    unsigned short* w1t  = (unsigned short*)(p + 393216);     // 131072 B (fp16)
    unsigned short* w2t  = (unsigned short*)(p + 524288);     // 131072 B (fp16)
    unsigned short* w3t  = (unsigned short*)(p + 655360);     // 4718592 B (fp16)
    int* slots           = (int*)(p + 10485760);              // gbar [0,512], flags [1024,1280)

    hipMemsetAsync(slots, 0, 8192, stream);
    rde_fused11<<<dim3(256), dim3(256), 0, stream>>>(
        x0, logsigs, iW1, ib1, iW2, ib2, iW3, ib3,
        vW1, vb1, vW2, vb2, vW3, vb3, roW, rob, out,
        hA, hB, hC, w1t, w2t, w3t, slots);
}